// Round 4
// baseline (64.527 us; speedup 1.0000x reference)
//
#include <hip/hip_runtime.h>
#include <hip/hip_bf16.h>

// SimilarityLayer: out[e,q,w,n,m] = <p[e,w,:,n], q[e,q,:,m]> / (|p||q| + 1e-8)
// E=8 W=5 C=640 N=49 Q=75.  Per e: GEMM [245 x 640] x [640 x 3675].
// R4: prep converts proto -> pre-swizzled bf16 A image (once) + partial norms.
//     GEMM: 464 blocks (e x 64-col tile), 256 thr, 2 blocks/CU (LDS = 80 KiB),
//     A via global_load_lds(16B) double-buffered, B fp32->bf16 with 2-deep
//     register prefetch, norms overlaid on dead LDS after the K-loop.

#define E_CNT 8
#define W_CNT 5
#define C_CNT 640
#define N_CNT 49
#define Q_CNT 75
#define QM_TOT (Q_CNT * N_CNT)      // 3675
#define MROWS (W_CNT * N_CNT)       // 245
#define NT64 58                     // ceil(3675/64)
#define ASW_BLK 32768               // 256 rows x 128 B per (e, chunk)
#define ASW_SIZE (E_CNT * 10 * ASW_BLK)
#define PN_OFF ASW_SIZE
#define PN_PART_BYTES (E_CNT * 10 * MROWS * 4)
#define WS_NEEDED ((size_t)(PN_OFF + PN_PART_BYTES))

// GEMM LDS: A dbuf 2x32768 @0 ; B dbuf 2x8192 @65536 ; total 81920 (2 blocks/CU)
#define B_OFF 65536
#define SM_BYTES 81920

typedef __attribute__((ext_vector_type(8))) short bf16x8;
typedef __attribute__((ext_vector_type(4))) float f32x4;

static __device__ __forceinline__ short f2bf(float f) {
    __hip_bfloat16 h = __float2bfloat16(f);
    return *reinterpret_cast<short*>(&h);
}

static __device__ __forceinline__ void gload16(const void* g, void* l) {
    __builtin_amdgcn_global_load_lds(
        (const __attribute__((address_space(1))) void*)g,
        (__attribute__((address_space(3))) void*)l, 16, 0, 0);
}

// ---------------- prep: proto -> swizzled bf16 A image + partial norms -------
__global__ __launch_bounds__(256, 4)
void prep_kernel(const float* __restrict__ proto,
                 unsigned char* __restrict__ asw,
                 float* __restrict__ pn_part)
{
    __shared__ float pns[MROWS];
    const int b = blockIdx.x;
    const int e = b / 10, cc = b % 10;
    const float* pbase = proto + (size_t)e * (W_CNT * C_CNT * N_CNT);
    unsigned char* abase = asw + (size_t)(e * 10 + cc) * ASW_BLK;
    const int t = threadIdx.x;
    if (t < MROWS) pns[t] = 0.f;
    __syncthreads();

    #pragma unroll
    for (int i = 0; i < 8; ++i) {
        const int s = t + i * 256;          // slot = kb*245 + nw
        if (s < 8 * MROWS) {
            const int kb = s / MROWS;
            const int nw = s - kb * MROWS;
            const int w = nw / N_CNT, n = nw - w * N_CNT;
            const float* g = pbase + ((size_t)(w * C_CNT + cc * 64 + kb * 8)) * N_CNT + n;
            float vv[8];
            #pragma unroll
            for (int j = 0; j < 8; ++j) vv[j] = g[(size_t)j * N_CNT];
            float ss = 0.f;
            bf16x8 pk;
            #pragma unroll
            for (int j = 0; j < 8; ++j) { const float f = vv[j]; ss += f * f; pk[j] = f2bf(f); }
            *reinterpret_cast<bf16x8*>(abase + nw * 128 + ((kb ^ (nw & 7)) << 4)) = pk;
            atomicAdd(&pns[nw], ss);
        } else {
            const int x = s - 8 * MROWS;    // zero-pad rows 245..255
            const int nw = MROWS + (x >> 3), kb = x & 7;
            *reinterpret_cast<bf16x8*>(abase + nw * 128 + ((kb ^ (nw & 7)) << 4)) =
                (bf16x8){0, 0, 0, 0, 0, 0, 0, 0};
        }
    }
    __syncthreads();
    if (t < MROWS) pn_part[(size_t)(e * 10 + cc) * MROWS + t] = pns[t];
}

// ---------------- GEMM: [256 x 640] x [640 x 64] per block -------------------
__global__ __launch_bounds__(256, 2)
void gemm_kernel(const float* __restrict__ query,
                 const unsigned char* __restrict__ asw,
                 const float* __restrict__ pn_part,
                 float* __restrict__ out)
{
    extern __shared__ unsigned char sm[];
    const int b = blockIdx.x;
    const int e = b & 7;                // one e per XCD -> A image L2-resident
    const int jt = b >> 3;
    const int qm0 = jt * 64;
    const int t = threadIdx.x;
    const int wv = t >> 6, ln = t & 63;
    const int lrow = ln & 15, lk = ln >> 4;

    // B staging: thread owns col r = t&63, granules kb0 and kb0+4
    const int r = t & 63;
    const int kb0 = t >> 6;             // 0..3
    const int qm = qm0 + r;
    const bool valid = qm < QM_TOT;
    const int q = valid ? (qm / N_CNT) : 0;
    const int m = valid ? (qm - q * N_CNT) : 0;
    const float* qsrc = query + (size_t)(e * Q_CNT + q) * (C_CNT * N_CNT) + m;
    const int bo0 = r * 128 + ((kb0 ^ (r & 7)) << 4);
    const int bo1 = r * 128 + (((kb0 + 4) ^ (r & 7)) << 4);

    const unsigned char* agl = asw + (size_t)(e * 10) * ASW_BLK;

    float vb[2][16];
    float ss_tot = 0.f;

    f32x4 acc[4][4];
    #pragma unroll
    for (int i = 0; i < 4; ++i)
        #pragma unroll
        for (int j = 0; j < 4; ++j) acc[i][j] = (f32x4){0.f, 0.f, 0.f, 0.f};

#define A_ISSUE(cc, buf) do {                                                   \
    const unsigned char* ag_ = agl + (size_t)(cc) * ASW_BLK;                    \
    _Pragma("unroll")                                                           \
    for (int i_ = 0; i_ < 8; ++i_)                                              \
        gload16(ag_ + (t + i_ * 256) * 16, sm + (buf) * 32768 + (t + i_ * 256) * 16); \
} while (0)

#define B_LOAD(cc, slot) do {                                                   \
    _Pragma("unroll")                                                           \
    for (int h_ = 0; h_ < 2; ++h_) {                                            \
        const size_t co_ = (size_t)((cc) * 64 + (kb0 + h_ * 4) * 8) * N_CNT;    \
        _Pragma("unroll")                                                       \
        for (int j_ = 0; j_ < 8; ++j_)                                          \
            vb[slot][h_ * 8 + j_] = valid ? qsrc[co_ + (size_t)j_ * N_CNT] : 0.f; \
    }                                                                           \
} while (0)

#define B_WRITE(slot, buf) do {                                                 \
    _Pragma("unroll")                                                           \
    for (int h_ = 0; h_ < 2; ++h_) {                                            \
        bf16x8 pk_; float s8_ = 0.f;                                            \
        _Pragma("unroll")                                                       \
        for (int j_ = 0; j_ < 8; ++j_) {                                        \
            const float f_ = vb[slot][h_ * 8 + j_]; s8_ += f_ * f_; pk_[j_] = f2bf(f_); \
        }                                                                       \
        ss_tot += s8_;                                                          \
        *reinterpret_cast<bf16x8*>(sm + B_OFF + (buf) * 8192 + (h_ ? bo1 : bo0)) = pk_; \
    }                                                                           \
} while (0)

    // prologue: B chunks 0,1 in flight; A chunk 0 staged
    B_LOAD(0, 0);
    B_LOAD(1, 1);
    A_ISSUE(0, 0);
    B_WRITE(0, 0);
    __syncthreads();

    for (int cc = 0; cc < 10; ++cc) {
        const int cur = cc & 1, nxt = cur ^ 1;
        if (cc < 9) A_ISSUE(cc + 1, nxt);
        if (cc < 8) B_LOAD(cc + 2, cur);    // 2-deep: full iteration of cover

        // MFMA on buffers [cur]
        {
            const unsigned char* Ab = sm + cur * 32768;
            const unsigned char* Bb = sm + B_OFF + cur * 8192;
            #pragma unroll
            for (int ks = 0; ks < 2; ++ks) {
                bf16x8 af[4], bfr[4];
                #pragma unroll
                for (int i = 0; i < 4; ++i) {
                    const int row = wv * 64 + i * 16 + lrow;
                    const int gr = (ks * 4 + lk) ^ (row & 7);
                    af[i] = *reinterpret_cast<const bf16x8*>(Ab + row * 128 + gr * 16);
                }
                #pragma unroll
                for (int j = 0; j < 4; ++j) {
                    const int cl = j * 16 + lrow;
                    const int gr = (ks * 4 + lk) ^ (cl & 7);
                    bfr[j] = *reinterpret_cast<const bf16x8*>(Bb + cl * 128 + gr * 16);
                }
                #pragma unroll
                for (int i = 0; i < 4; ++i)
                    #pragma unroll
                    for (int j = 0; j < 4; ++j)
                        acc[i][j] = __builtin_amdgcn_mfma_f32_16x16x32_bf16(
                            af[i], bfr[j], acc[i][j], 0, 0, 0);
            }
        }

        if (cc < 9) B_WRITE(nxt, nxt);      // B(cc+1), loaded a full iter ago
        __syncthreads();
    }

    // ---- norms (overlay dead A buffer) ----
    float* qn = (float*)sm;                 // 64 f32
    float* pnl = (float*)(sm + 256);        // 245 f32
    if (t < 64) qn[t] = 0.f;
    __syncthreads();
    atomicAdd(&qn[r], ss_tot);              // 4 threads per col r
    if (t < MROWS) {
        float s = 0.f;
        #pragma unroll
        for (int cc = 0; cc < 10; ++cc) s += pn_part[(size_t)(e * 10 + cc) * MROWS + t];
        pnl[t] = sqrtf(s);
    }
    __syncthreads();

    // ---- epilogue ----
    float nq4[4];
    int cl4[4];
    #pragma unroll
    for (int j = 0; j < 4; ++j) {
        cl4[j] = j * 16 + lrow;
        nq4[j] = sqrtf(qn[cl4[j]]);
    }
    #pragma unroll
    for (int i = 0; i < 4; ++i) {
        #pragma unroll
        for (int rr = 0; rr < 4; ++rr) {
            const int nw = wv * 64 + i * 16 + lk * 4 + rr;   // D row
            if (nw < MROWS) {
                const float np_ = pnl[nw];
                const int w = nw / N_CNT, n = nw - w * N_CNT;
                #pragma unroll
                for (int j = 0; j < 4; ++j) {
                    const int qmj = qm0 + cl4[j];
                    if (qmj < QM_TOT) {
                        const int qq = qmj / N_CNT, mm = qmj - qq * N_CNT;
                        const float den = np_ * nq4[j] + 1e-8f;
                        out[(((size_t)(e * Q_CNT + qq) * W_CNT + w) * N_CNT + n) * N_CNT + mm] =
                            acc[i][j][rr] * __builtin_amdgcn_rcpf(den);
                    }
                }
            }
        }
    }
#undef A_ISSUE
#undef B_LOAD
#undef B_WRITE
}

// ---------------- fallback (R2 kernel) if ws too small -----------------------
struct SMemFB {
    unsigned char A[256 * 128];
    unsigned char B[64 * 128];
    float ns[320];
};

__global__ __launch_bounds__(512, 4)
void sim_fallback_kernel(const float* __restrict__ proto,
                         const float* __restrict__ query,
                         float* __restrict__ out)
{
    __shared__ SMemFB smf;
    const int t = threadIdx.x;
    const int e = blockIdx.x / Q_CNT;
    const int q = blockIdx.x - e * Q_CNT;
    const float* pbase = proto + (size_t)e * (W_CNT * C_CNT * N_CNT);
    const float* qbase = query + ((size_t)e * Q_CNT + q) * (C_CNT * N_CNT);
    unsigned char* lds = (unsigned char*)&smf;
    if (t < 320) smf.ns[t] = 0.f;
    if (t < 208) {
        if (t < 88) *reinterpret_cast<f32x4*>(smf.A + 245 * 128 + t * 16) = (f32x4){0.f,0.f,0.f,0.f};
        else        *reinterpret_cast<f32x4*>(smf.B + 49 * 128 + (t - 88) * 16) = (f32x4){0.f,0.f,0.f,0.f};
    }
    const int nslot5 = (t < 304);
    const float* gp[5];
    int offidx[5];
    #pragma unroll
    for (int i = 0; i < 5; ++i) {
        gp[i] = pbase; offidx[i] = 0;
        if (i < 4 || nslot5) {
            const int s = t + i * 512;
            if (s < 1960) {
                const int kb = s / 245, nw = s - kb * 245;
                const int w = nw / 49, n = nw - w * 49;
                gp[i] = pbase + ((size_t)w * C_CNT + kb * 8) * N_CNT + n;
                offidx[i] = (nw * 128 + ((kb ^ (nw & 7)) << 4)) | (nw << 16);
            } else {
                const int s2 = s - 1960;
                const int kb = s2 / 49, mq = s2 - kb * 49;
                gp[i] = qbase + (size_t)(kb * 8) * N_CNT + mq;
                offidx[i] = (32768 + mq * 128 + ((kb ^ (mq & 7)) << 4)) | ((256 + mq) << 16);
            }
        }
    }
    float v[5][8];
    float ss[5] = {0.f,0.f,0.f,0.f,0.f};
    #pragma unroll
    for (int i = 0; i < 4; ++i)
        #pragma unroll
        for (int j = 0; j < 8; ++j) v[i][j] = gp[i][(size_t)j * N_CNT];
    if (nslot5)
        #pragma unroll
        for (int j = 0; j < 8; ++j) v[4][j] = gp[4][(size_t)j * N_CNT];
    f32x4 acc[2][4];
    #pragma unroll
    for (int i = 0; i < 2; ++i)
        #pragma unroll
        for (int j = 0; j < 4; ++j) acc[i][j] = (f32x4){0.f,0.f,0.f,0.f};
    const int wv = t >> 6, ln = t & 63, lrow = ln & 15, lk = ln >> 4;
    for (int kc = 0; kc < 10; ++kc) {
        #pragma unroll
        for (int i = 0; i < 5; ++i) {
            if (i < 4 || nslot5) {
                bf16x8 pk; float s8 = 0.f;
                #pragma unroll
                for (int j = 0; j < 8; ++j) { const float f = v[i][j]; s8 += f*f; pk[j] = f2bf(f); }
                ss[i] += s8;
                *reinterpret_cast<bf16x8*>(lds + (offidx[i] & 0xFFFF)) = pk;
            }
        }
        __syncthreads();
        if (kc < 9) {
            #pragma unroll
            for (int i = 0; i < 4; ++i) {
                gp[i] += 64 * N_CNT;
                #pragma unroll
                for (int j = 0; j < 8; ++j) v[i][j] = gp[i][(size_t)j * N_CNT];
            }
            if (nslot5) {
                gp[4] += 64 * N_CNT;
                #pragma unroll
                for (int j = 0; j < 8; ++j) v[4][j] = gp[4][(size_t)j * N_CNT];
            }
        }
        #pragma unroll
        for (int ks = 0; ks < 2; ++ks) {
            bf16x8 af[2], bfr[4];
            #pragma unroll
            for (int i = 0; i < 2; ++i) {
                const int row = (wv * 2 + i) * 16 + lrow;
                const int gr = (ks * 4 + lk) ^ (row & 7);
                af[i] = *reinterpret_cast<const bf16x8*>(lds + row * 128 + gr * 16);
            }
            #pragma unroll
            for (int j = 0; j < 4; ++j) {
                const int mq = j * 16 + lrow;
                const int gr = (ks * 4 + lk) ^ (mq & 7);
                bfr[j] = *reinterpret_cast<const bf16x8*>(lds + 32768 + mq * 128 + gr * 16);
            }
            #pragma unroll
            for (int i = 0; i < 2; ++i)
                #pragma unroll
                for (int j = 0; j < 4; ++j)
                    acc[i][j] = __builtin_amdgcn_mfma_f32_16x16x32_bf16(af[i], bfr[j], acc[i][j], 0, 0, 0);
        }
        __syncthreads();
    }
    #pragma unroll
    for (int i = 0; i < 5; ++i)
        if (i < 4 || nslot5) atomicAdd(&smf.ns[offidx[i] >> 16], ss[i]);
    __syncthreads();
    float nq[4];
    #pragma unroll
    for (int j = 0; j < 4; ++j) {
        const int mq = j * 16 + lrow;
        nq[j] = (mq < N_CNT) ? sqrtf(smf.ns[256 + mq]) : 1.f;
    }
    float* obase = out + (size_t)(e * Q_CNT + q) * (W_CNT * N_CNT * N_CNT);
    #pragma unroll
    for (int i = 0; i < 2; ++i) {
        #pragma unroll
        for (int rr = 0; rr < 4; ++rr) {
            const int nw = (wv * 2 + i) * 16 + lk * 4 + rr;
            if (nw < W_CNT * N_CNT) {
                const int w = nw / 49, n = nw - w * 49;
                const float np_ = sqrtf(smf.ns[nw]);
                float* orow = obase + ((size_t)w * N_CNT + n) * N_CNT;
                #pragma unroll
                for (int j = 0; j < 4; ++j) {
                    const int mq = j * 16 + lrow;
                    if (mq < N_CNT) orow[mq] = acc[i][j][rr] / (np_ * nq[j] + 1e-8f);
                }
            }
        }
    }
}

extern "C" void kernel_launch(void* const* d_in, const int* in_sizes, int n_in,
                              void* d_out, int out_size, void* d_ws, size_t ws_size,
                              hipStream_t stream)
{
    const float* proto = (const float*)d_in[0];
    const float* query = (const float*)d_in[1];
    float* out = (float*)d_out;

    if (ws_size < WS_NEEDED) {
        hipLaunchKernelGGL(sim_fallback_kernel, dim3(E_CNT * Q_CNT), dim3(512), 0, stream,
                           proto, query, out);
        return;
    }

    unsigned char* asw = (unsigned char*)d_ws;
    float* pn_part = (float*)((unsigned char*)d_ws + PN_OFF);

    hipLaunchKernelGGL(prep_kernel, dim3(E_CNT * 10), dim3(256), 0, stream,
                       proto, asw, pn_part);
    hipLaunchKernelGGL(gemm_kernel, dim3(E_CNT * NT64), dim3(256), SM_BYTES, stream,
                       query, asw, pn_part, out);
}